// Round 11
// baseline (2481.782 us; speedup 1.0000x reference)
//
#include <hip/hip_runtime.h>
#include <hip/hip_bf16.h>

// NonlinearReservoirCell: B=262144 rows, M=3 independent tiny MLPs
//   free_water = last_free_water + sum_n runoff
//   a1 = relu(runoff @ W1 + b1)   (256 -> 256)
//   a2 = relu(a1 @ W2 + b2)       (256 -> 128)
//   ratio = sigmoid(a2 @ W3 + b3) (128 -> 1)
//   flow = fw*ratio + last_flow*(1-ratio);  new_fw = fw - flow
// R11: dense 64-row units, ONE 512-thread block/CU (8 waves = 2/SIMD).
//   - weight fragments amortized over 64 rows (576 KB/unit L2 traffic, half
//     of R9/R10) via h/k2 wave-split: wave (rh=wv>>2, hs=wv&3).
//   - T14 stage with BOUNDED regs: 6 pairs issued at m0 (48 VGPR), cvt at m1
//     (-> preU[0..5]), 6 more at m1, cvt at m2; write-late after m2-L1 bar.
//   - R10 lesson (1.1 GB spill writes): never co-hold bulk weight preloads;
//     W1/W2 stream with +1-deep ring (32 regs).

#define B_TOT 262144
#define M_    3
#define N_    256
#define H1_   256
#define H2_   128
#define BM_   (B_TOT * M_)
#define ROWS_BLK 512
#define UNITS    8        // 8 units x 64 rows

typedef __bf16 bf16_t;
typedef __bf16  bf16x8 __attribute__((ext_vector_type(8)));
typedef float   f32x16 __attribute__((ext_vector_type(16)));
typedef float   f32x4  __attribute__((ext_vector_type(4)));

__device__ __forceinline__ unsigned pack_bf2(float lo, float hi) {
  union { bf16_t b; unsigned short u; } a, c;
  a.b = (bf16_t)lo; c.b = (bf16_t)hi;
  return ((unsigned)c.u << 16) | (unsigned)a.u;
}

// ---------------------------------------------------------------------------
// Prep: transpose + cvt weights into per-lane MFMA A-fragment order (bf16).
// w1s[m][kk(16)][t(8)][lane(64)][ii(8)] = bf16(W1[m][n=16kk+8*(lane>>5)+ii][h=32t+(lane&31)])
// w2s[m][kk2(16)][t2(4)][lane(64)][ii(8)] = bf16(W2[m][h=16kk2+8*(lane>>5)+ii][k2=32t2+(lane&31)])
// ---------------------------------------------------------------------------
__global__ __launch_bounds__(256) void prep_weights(
    const float* __restrict__ W1, const float* __restrict__ W2,
    bf16_t* __restrict__ w1s, bf16_t* __restrict__ w2s)
{
  int id = blockIdx.x * 256 + threadIdx.x;
  const int NW1 = M_ * 16 * 8 * 64;   // 24576 groups of 8
  const int NW2 = M_ * 16 * 4 * 64;   // 12288 groups of 8
  if (id < NW1) {
    int lane = id & 63;
    int t    = (id >> 6) & 7;
    int kk   = (id >> 9) & 15;
    int m    = id >> 13;
    int h  = 32 * t + (lane & 31);
    int n0 = 16 * kk + 8 * (lane >> 5);
    bf16x8 v;
#pragma unroll
    for (int ii = 0; ii < 8; ++ii)
      v[ii] = (bf16_t)W1[((size_t)m * N_ + (n0 + ii)) * H1_ + h];
    *reinterpret_cast<bf16x8*>(&w1s[(size_t)id * 8]) = v;
  } else if (id < NW1 + NW2) {
    int j    = id - NW1;
    int lane = j & 63;
    int t2   = (j >> 6) & 3;
    int kk2  = (j >> 8) & 15;
    int m    = j >> 12;
    int k2 = 32 * t2 + (lane & 31);
    int h0 = 16 * kk2 + 8 * (lane >> 5);
    bf16x8 v;
#pragma unroll
    for (int ii = 0; ii < 8; ++ii)
      v[ii] = (bf16_t)W2[((size_t)m * H1_ + (h0 + ii)) * H2_ + k2];
    *reinterpret_cast<bf16x8*>(&w2s[(size_t)j * 8]) = v;
  }
}

// ---------------------------------------------------------------------------
// Main kernel. grid = 512, block = 512 thr = 8 waves, 1 block/CU.
// Wave (rh = wv>>2, hs = wv&3): rows [32rh, 32rh+32);
//   L1 h-slice [64hs, 64hs+64); L2 k2-slice [32hs, 32hs+32).
// ---------------------------------------------------------------------------
__global__ __launch_bounds__(512, 2) void reservoir_kernel(
    const float* __restrict__ last_flow,
    const float* __restrict__ last_fw,
    const float* __restrict__ runoff,
    const float* __restrict__ b1,
    const float* __restrict__ b2,
    const float* __restrict__ W3,
    const float* __restrict__ b3,
    const bf16_t* __restrict__ w1s,
    const bf16_t* __restrict__ w2s,
    float* __restrict__ out)
{
  // sXP: [64 rows][768 bf16] full 3-KB rows. 16-B granules within each
  // m-group swizzled: phys = (c32&~31) | ((c32&31) ^ (row&31)). 96 KB.
  __shared__ alignas(16) bf16_t sXP[64 * 768];
  // sY: [64 rows][256 bf16] a1 panel, R9-verified swizzle. 32 KB.
  __shared__ alignas(16) bf16_t sY[64 * 256];
  __shared__ float sPart[M_][4][64];
  __shared__ float sRsum[M_][64];

  const int tid  = threadIdx.x;
  const int lane = tid & 63;
  const int wv   = tid >> 6;       // 0..7
  const int hi   = lane >> 5;
  const int r    = lane & 31;
  const int r15  = r & 15;
  const int rh   = wv >> 2;        // row half
  const int hs   = wv & 3;         // h/k2 slice
  const int myrow = rh * 32 + r;

  const size_t rbase = (size_t)blockIdx.x * ROWS_BLK;

  // ---- prologue: stage unit 0 (load-cvt-write immediately) ----
  {
    const float* src = runoff + rbase * (M_ * N_);
#pragma unroll
    for (int k = 0; k < 12; ++k) {
      const int o   = k * 512 + tid;           // 32-B chunk in [0,6144)
      f32x4 va = __builtin_nontemporal_load(
          reinterpret_cast<const f32x4*>(src + (size_t)o * 8));
      f32x4 vb = __builtin_nontemporal_load(
          reinterpret_cast<const f32x4*>(src + (size_t)o * 8 + 4));
      uint4 d;
      d.x = pack_bf2(va[0], va[1]);  d.y = pack_bf2(va[2], va[3]);
      d.z = pack_bf2(vb[0], vb[1]);  d.w = pack_bf2(vb[2], vb[3]);
      const int row  = o / 96;
      const int c32  = o - row * 96;
      const int phys = (c32 & ~31) | ((c32 & 31) ^ (row & 31));
      *reinterpret_cast<uint4*>(&sXP[row * 768 + phys * 8]) = d;
    }
  }
  __syncthreads();

  f32x4 tA[12];     // 6 in-flight load pairs (48 VGPR, one m-pass lifetime)
  uint4 preU[12];   // packed next-unit panel (48 VGPR, m1..m2 lifetime)

  for (int u = 0; u < UNITS; ++u) {
    const bool pf = (u + 1 < UNITS);
    const float* nsrc = runoff + (rbase + (size_t)(u + 1) * 64) * (M_ * N_);

#pragma unroll
    for (int m = 0; m < M_; ++m) {
      // ---- stage hooks (bounded transients) ----
      if (m == 0 && pf) {
#pragma unroll
        for (int p = 0; p < 6; ++p) {
          const int o = p * 512 + tid;
          tA[2 * p]     = __builtin_nontemporal_load(
              reinterpret_cast<const f32x4*>(nsrc + (size_t)o * 8));
          tA[2 * p + 1] = __builtin_nontemporal_load(
              reinterpret_cast<const f32x4*>(nsrc + (size_t)o * 8 + 4));
        }
        __builtin_amdgcn_sched_barrier(0);
      }
      if (m == 1 && pf) {
#pragma unroll
        for (int p = 0; p < 6; ++p) {
          preU[p].x = pack_bf2(tA[2 * p][0],     tA[2 * p][1]);
          preU[p].y = pack_bf2(tA[2 * p][2],     tA[2 * p][3]);
          preU[p].z = pack_bf2(tA[2 * p + 1][0], tA[2 * p + 1][1]);
          preU[p].w = pack_bf2(tA[2 * p + 1][2], tA[2 * p + 1][3]);
        }
#pragma unroll
        for (int p = 0; p < 6; ++p) {
          const int o = (6 + p) * 512 + tid;
          tA[2 * p]     = __builtin_nontemporal_load(
              reinterpret_cast<const f32x4*>(nsrc + (size_t)o * 8));
          tA[2 * p + 1] = __builtin_nontemporal_load(
              reinterpret_cast<const f32x4*>(nsrc + (size_t)o * 8 + 4));
        }
        __builtin_amdgcn_sched_barrier(0);
      }
      if (m == 2 && pf) {
#pragma unroll
        for (int p = 0; p < 6; ++p) {
          preU[6 + p].x = pack_bf2(tA[2 * p][0],     tA[2 * p][1]);
          preU[6 + p].y = pack_bf2(tA[2 * p][2],     tA[2 * p][3]);
          preU[6 + p].z = pack_bf2(tA[2 * p + 1][0], tA[2 * p + 1][1]);
          preU[6 + p].w = pack_bf2(tA[2 * p + 1][2], tA[2 * p + 1][3]);
        }
      }

      const bf16_t* w1m = w1s + (size_t)m * 65536;
      const bf16_t* w2m = w2s + (size_t)m * 32768;

      // ---------------- Layer 1: h-slice [64hs, 64hs+64), own rows --------
      f32x16 a0 = f32x16{}, a1m = f32x16{};
      float rs = 0.f;
      const bf16_t* xrow = &sXP[myrow * 768 + m * 32 * 8];
      bf16x8 wc0 = *reinterpret_cast<const bf16x8*>(
          w1m + (size_t)0 * 4096 + (2 * hs + 0) * 512 + lane * 8);
      bf16x8 wc1 = *reinterpret_cast<const bf16x8*>(
          w1m + (size_t)0 * 4096 + (2 * hs + 1) * 512 + lane * 8);
#pragma unroll
      for (int kk = 0; kk < 16; ++kk) {
        bf16x8 wn0{}, wn1{};
        if (kk < 15) {
          wn0 = *reinterpret_cast<const bf16x8*>(
              w1m + (size_t)(kk + 1) * 4096 + (2 * hs + 0) * 512 + lane * 8);
          wn1 = *reinterpret_cast<const bf16x8*>(
              w1m + (size_t)(kk + 1) * 4096 + (2 * hs + 1) * 512 + lane * 8);
        }
        const int j = 2 * kk + hi;
        bf16x8 bf = *reinterpret_cast<const bf16x8*>(&xrow[(j ^ r) * 8]);
        if (hs == m) {
#pragma unroll
          for (int i = 0; i < 8; ++i) rs += (float)bf[i];
        }
        a0  = __builtin_amdgcn_mfma_f32_32x32x16_bf16(wc0, bf, a0, 0, 0, 0);
        a1m = __builtin_amdgcn_mfma_f32_32x32x16_bf16(wc1, bf, a1m, 0, 0, 0);
        wc0 = wn0; wc1 = wn1;
      }
      if (hs == m) {
        rs += __shfl_xor(rs, 32, 64);
        if (hi == 0) sRsum[m][myrow] = rs;
      }
      __syncthreads();   // bar_a: prev sY readers done; (m==2) sXP readers done

      // ---- write-late: sXP(u+1) after last reader ----
      if (m == 2 && pf) {
#pragma unroll
        for (int k = 0; k < 12; ++k) {
          const int o    = k * 512 + tid;
          const int row  = o / 96;
          const int c32  = o - row * 96;
          const int phys = (c32 & ~31) | ((c32 & 31) ^ (row & 31));
          *reinterpret_cast<uint4*>(&sXP[row * 768 + phys * 8]) = preU[k];
        }
      }

      // a1 = relu(acc + b1) -> sY
      const float* b1m = b1 + m * H1_;
#pragma unroll
      for (int tl = 0; tl < 2; ++tl) {
        const int tg = 2 * hs + tl;
        const f32x16& ac = (tl == 0) ? a0 : a1m;
#pragma unroll
        for (int g2 = 0; g2 < 4; ++g2) {
          const int hb = 32 * tg + 8 * g2 + 4 * hi;
          f32x4 bv = *reinterpret_cast<const f32x4*>(&b1m[hb]);
          uint2 d;
          d.x = pack_bf2(fmaxf(ac[4 * g2 + 0] + bv[0], 0.f),
                         fmaxf(ac[4 * g2 + 1] + bv[1], 0.f));
          d.y = pack_bf2(fmaxf(ac[4 * g2 + 2] + bv[2], 0.f),
                         fmaxf(ac[4 * g2 + 3] + bv[3], 0.f));
          const int G = 4 * tg + g2;
          *reinterpret_cast<uint2*>(
              &sY[myrow * 256 + ((G ^ r15) * 8) + hi * 4]) = d;
        }
      }
      __syncthreads();   // bar_b: sY(m) ready (and sXP(u+1) if m==2)

      // ---------------- Layer 2: k2-slice [32hs, 32hs+32), own rows -------
      f32x16 c2 = f32x16{};
      bf16x8 v0 = *reinterpret_cast<const bf16x8*>(
          w2m + (size_t)0 * 2048 + hs * 512 + lane * 8);
#pragma unroll
      for (int kk2 = 0; kk2 < 16; ++kk2) {
        bf16x8 vn{};
        if (kk2 < 15)
          vn = *reinterpret_cast<const bf16x8*>(
              w2m + (size_t)(kk2 + 1) * 2048 + hs * 512 + lane * 8);
        bf16x8 bf = *reinterpret_cast<const bf16x8*>(
            &sY[myrow * 256 + (((2 * kk2 + hi) ^ r15) * 8)]);
        c2 = __builtin_amdgcn_mfma_f32_32x32x16_bf16(v0, bf, c2, 0, 0, 0);
        v0 = vn;
      }

      // ---------------- Layer 3 partial ----------------
      const float* b2m = b2 + m * H2_;
      const float* w3m = W3 + m * H2_;
      float part = 0.f;
#pragma unroll
      for (int e = 0; e < 16; ++e) {
        const int k2 = 32 * hs + (e & 3) + 8 * (e >> 2) + 4 * hi;
        part += fmaxf(c2[e] + b2m[k2], 0.f) * w3m[k2];
      }
      part += __shfl_xor(part, 32, 64);
      if (hi == 0) sPart[m][hs][myrow] = part;
    }   // m loop

    __syncthreads();   // bar_c: all sPart/sRsum visible

    // ---------------- epilogue: one thread per row ----------------
    if (tid < 64) {
      const size_t grow = rbase + (size_t)u * 64 + tid;
#pragma unroll
      for (int m = 0; m < M_; ++m) {
        const size_t oi   = grow * M_ + m;
        const float pt    = sPart[m][0][tid] + sPart[m][1][tid]
                          + sPart[m][2][tid] + sPart[m][3][tid] + b3[m];
        const float ratio = 1.0f / (1.0f + __expf(-pt));
        const float fw    = last_fw[oi] + sRsum[m][tid];
        const float lf    = last_flow[oi];
        const float flow  = fw * ratio + lf * (1.0f - ratio);
        out[oi]       = fw - flow;   // new_free_water
        out[BM_ + oi] = flow;        // flow
      }
    }
    __syncthreads();   // bar_d: epilogue done before next unit's writers
  }
}

// ---------------------------------------------------------------------------
extern "C" void kernel_launch(void* const* d_in, const int* in_sizes, int n_in,
                              void* d_out, int out_size, void* d_ws, size_t ws_size,
                              hipStream_t stream) {
  const float* last_flow = (const float*)d_in[0];
  const float* last_fw   = (const float*)d_in[1];
  const float* runoff    = (const float*)d_in[2];
  const float* W1 = (const float*)d_in[3];
  const float* b1 = (const float*)d_in[4];
  const float* W2 = (const float*)d_in[5];
  const float* b2 = (const float*)d_in[6];
  const float* W3 = (const float*)d_in[7];
  const float* b3 = (const float*)d_in[8];
  float* out = (float*)d_out;

  bf16_t* w1s = (bf16_t*)d_ws;                    // 3*65536 bf16 = 384 KB
  bf16_t* w2s = w1s + (size_t)M_ * 65536;         // 3*32768 bf16 = 192 KB

  prep_weights<<<144, 256, 0, stream>>>(W1, W2, w1s, w2s);

  reservoir_kernel<<<B_TOT / ROWS_BLK, 512, 0, stream>>>(
      last_flow, last_fw, runoff, b1, b2, W3, b3, w1s, w2s, out);
}